// Round 2
// baseline (1227.625 us; speedup 1.0000x reference)
//
#include <hip/hip_runtime.h>
#include <hip/hip_bf16.h>
#include <math.h>

typedef __hip_bfloat16 bf16;
typedef unsigned short u16;
typedef __attribute__((ext_vector_type(8))) short short8;
typedef __attribute__((ext_vector_type(4))) float f32x4;

#define PP 1024
#define LL 32
#define EE 512
#define DD 768
#define NLAYER 6
#define FFDIM 3072

__device__ __forceinline__ float bf2f(u16 u) { return __uint_as_float(((unsigned)u) << 16); }
// fp32 -> bf16 (RNE), finite inputs only
__device__ __forceinline__ u16 f2b(float x) {
  unsigned u = __float_as_uint(x);
  return (u16)((u + 0x7FFFu + ((u >> 16) & 1u)) >> 16);
}

// ---------------------------------------------------------------------------
// emb_table[r][k] = byte_emb[r>>5][k] + local_pos[r&31][k], bf16 out.
// [8192, 512]: one row per (token value, local position) pair.
// ---------------------------------------------------------------------------
__global__ __launch_bounds__(256) void embed_table(
    const float* __restrict__ be, const float* __restrict__ lp, bf16* __restrict__ T)
{
  int i = blockIdx.x * 256 + threadIdx.x;   // 8192 * 64 threads, 8 elems each
  int r = i >> 6, c = (i & 63) << 3;
  int t = r >> 5, l = r & 31;
  const float* bp = be + ((long)t << 9) + c;
  const float* pp = lp + ((long)l << 9) + c;
  float4 x0 = *(const float4*)bp, x1 = *(const float4*)(bp + 4);
  float4 y0 = *(const float4*)pp, y1 = *(const float4*)(pp + 4);
  short8 o;
  o[0] = (short)f2b(x0.x + y0.x); o[1] = (short)f2b(x0.y + y0.y);
  o[2] = (short)f2b(x0.z + y0.z); o[3] = (short)f2b(x0.w + y0.w);
  o[4] = (short)f2b(x1.x + y1.x); o[5] = (short)f2b(x1.y + y1.y);
  o[6] = (short)f2b(x1.z + y1.z); o[7] = (short)f2b(x1.w + y1.w);
  *(short8*)((u16*)T + ((long)r << 9) + c) = o;
}

// ---------------------------------------------------------------------------
// C = A @ B^T (+bias)(+addf)(gelu / atomic). A bf16 [M,K]. B bf16 [N,K] or
// (BF32) fp32 [N,K] converted to bf16 (RNE, identical bits to a separate
// cvt pass) during LDS staging -- weight n-tiles stay L2-resident since
// blockIdx.x = m-tile is fastest, so the fp32 re-reads hit L2.
// 64x64 tile / 256 threads, BK=64, double-buffered LDS, one barrier per
// chunk, next chunk's global loads issued before this chunk's MFMAs.
// act: 0 = none, 1 = gelu, 2 = split-K atomicAdd into fp32 Cf (bias only
// from bz==0; addf must be null; Cf must hold the residual/init value).
// Split-K / batching via blockIdx.z: sAb/sBb are element offsets (K-offset
// for split-K, batch stride otherwise); sCb is the C batch offset.
// M % 64 == 0; N, K guarded (K tail of 32).
// ---------------------------------------------------------------------------
template<bool BF32>
__global__ __launch_bounds__(256) void gemm64(
    const bf16* A, long sAb, int lda,
    const void* B, long sBb, int ldb,
    float* Cf, bf16* Cb, long sCb, int ldc,
    const float* bias, int biasStride,
    const float* addf,
    int M, int N, int K, int act)
{
  __shared__ u16 As[2][64][72];   // stride 144 B: 16B-aligned, 2-way-only banks
  __shared__ u16 Bs[2][64][72];
  const int bz = blockIdx.z;
  const u16* Ap = (const u16*)A + (long)bz * sAb;
  const u16* Bp = (const u16*)B + (long)bz * sBb;
  const float* Bfp = (const float*)B + (long)bz * sBb;
  const long coff = (long)bz * sCb;
  const int m0 = blockIdx.x << 6, n0 = blockIdx.y << 6;
  const int tid = threadIdx.x;
  const int wave = tid >> 6, lane = tid & 63;
  const int sr = tid >> 3;          // staging row 0..31 (and +32)
  const int scc = (tid & 7) << 3;   // staging col 0..56
  const int br0 = n0 + sr, br1 = n0 + sr + 32;
  const short8 zz = {0,0,0,0,0,0,0,0};
  f32x4 acc[4] = {{0.f,0.f,0.f,0.f},{0.f,0.f,0.f,0.f},{0.f,0.f,0.f,0.f},{0.f,0.f,0.f,0.f}};

#define LOADB(row, kk, dest)                                                   \
  do {                                                                         \
    if (!BF32) {                                                               \
      dest = *(const short8*)(Bp + (long)(row) * ldb + (kk));                  \
    } else {                                                                   \
      const float* fp_ = Bfp + (long)(row) * ldb + (kk);                       \
      float4 x0_ = *(const float4*)fp_, x1_ = *(const float4*)(fp_ + 4);       \
      dest[0] = (short)f2b(x0_.x); dest[1] = (short)f2b(x0_.y);                \
      dest[2] = (short)f2b(x0_.z); dest[3] = (short)f2b(x0_.w);                \
      dest[4] = (short)f2b(x1_.x); dest[5] = (short)f2b(x1_.y);                \
      dest[6] = (short)f2b(x1_.z); dest[7] = (short)f2b(x1_.w);                \
    }                                                                          \
  } while (0)

  // prologue: stage chunk 0 into buffer 0
  {
    int ch = K < 64 ? K : 64;
    bool kv = scc < ch;
    short8 a0 = zz, a1 = zz, b0 = zz, b1 = zz;
    if (kv) {
      a0 = *(const short8*)(Ap + (long)(m0 + sr) * lda + scc);
      a1 = *(const short8*)(Ap + (long)(m0 + sr + 32) * lda + scc);
      if (br0 < N) LOADB(br0, scc, b0);
      if (br1 < N) LOADB(br1, scc, b1);
    }
    *(short8*)&As[0][sr][scc] = a0;
    *(short8*)&As[0][sr + 32][scc] = a1;
    *(short8*)&Bs[0][sr][scc] = b0;
    *(short8*)&Bs[0][sr + 32][scc] = b1;
  }
  __syncthreads();

  const int arow = (wave << 4) + (lane & 15);
  const int kq = (lane >> 4) << 3;
  int buf = 0;
  for (int k0 = 0; k0 < K; k0 += 64) {
    int knext = k0 + 64;
    bool more = knext < K;
    short8 a0 = zz, a1 = zz, b0 = zz, b1 = zz;
    if (more) {   // issue next chunk's loads before MFMAs (overlap)
      int ch = K - knext; if (ch > 64) ch = 64;
      bool kv = scc < ch;
      if (kv) {
        a0 = *(const short8*)(Ap + (long)(m0 + sr) * lda + knext + scc);
        a1 = *(const short8*)(Ap + (long)(m0 + sr + 32) * lda + knext + scc);
        if (br0 < N) LOADB(br0, knext + scc, b0);
        if (br1 < N) LOADB(br1, knext + scc, b1);
      }
    }
    int rem = K - k0; if (rem > 64) rem = 64;
    {
      short8 af = *(const short8*)&As[buf][arow][kq];
#pragma unroll
      for (int nt = 0; nt < 4; nt++) {
        short8 bfr = *(const short8*)&Bs[buf][(nt << 4) + (lane & 15)][kq];
        acc[nt] = __builtin_amdgcn_mfma_f32_16x16x32_bf16(af, bfr, acc[nt], 0, 0, 0);
      }
    }
    if (rem > 32) {
      short8 af = *(const short8*)&As[buf][arow][32 + kq];
#pragma unroll
      for (int nt = 0; nt < 4; nt++) {
        short8 bfr = *(const short8*)&Bs[buf][(nt << 4) + (lane & 15)][32 + kq];
        acc[nt] = __builtin_amdgcn_mfma_f32_16x16x32_bf16(af, bfr, acc[nt], 0, 0, 0);
      }
    }
    if (more) {
      int nb = buf ^ 1;
      *(short8*)&As[nb][sr][scc] = a0;
      *(short8*)&As[nb][sr + 32][scc] = a1;
      *(short8*)&Bs[nb][sr][scc] = b0;
      *(short8*)&Bs[nb][sr + 32][scc] = b1;
      __syncthreads();
      buf = nb;
    }
  }
#undef LOADB

  int rbase = m0 + (wave << 4) + ((lane >> 4) << 2);
#pragma unroll
  for (int nt = 0; nt < 4; nt++) {
    int c = n0 + (nt << 4) + (lane & 15);
    if (c >= N) continue;
    float bvl = bias ? bias[bz * biasStride + c] : 0.f;
    if (act == 2 && bz != 0) bvl = 0.f;
#pragma unroll
    for (int j = 0; j < 4; j++) {
      int r = rbase + j;
      long idx = coff + (long)r * ldc + c;
      float v = acc[nt][j] + bvl;
      if (addf) v += addf[idx];
      if (act == 1) v = 0.5f * v * (1.f + erff(v * 0.70710678118654752f));
      if (act == 2) {
        atomicAdd(Cf + idx, v);
      } else {
        if (Cf) Cf[idx] = v;
        if (Cb) Cb[idx] = __float2bfloat16(v);
      }
    }
  }
}

// ---------------------------------------------------------------------------
// Per-patch MHA over 32 bytes (4 heads, d=128) fused with masked mean.
// Q/K come from the per-(token,pos) table qkt [8192,1024]: row for byte j of
// patch p is (tokens[p*32+j]<<5)|j. MFMA QK^T (no LDS, no spills): wave =
// head; 2x2 16x16 C-tiles, 4 k-chunks.
// Softmax + column-mean via shuffle reductions in MFMA C-layout
// (row = (lane>>4)*4 + reg + ti*16, col = (lane&15) + tj*16).
// V path commuted: z_h = wsum_h @ emb (emb recomputed from fp32 tables).
// ---------------------------------------------------------------------------
__global__ __launch_bounds__(256) void patch_attn(
    const bf16* __restrict__ qkt,  // [8192, 1024] = [Q|K] per (token,pos)
    const int* __restrict__ tokens, const int* __restrict__ lengths,
    const float* __restrict__ byte_emb, const float* __restrict__ local_pos,
    bf16* __restrict__ Z)          // [1024, 4, 512]
{
  __shared__ float wsum[4][32];
  __shared__ int tok_s[32];
  __shared__ int cnt_s;
  int p = blockIdx.x;
  int tid = threadIdx.x;
  if (tid < 32) tok_s[tid] = tokens[p * 32 + tid];
  if (tid == 0) cnt_s = lengths[p];
  __syncthreads();
  int cnt = cnt_s;
  int h = tid >> 6, lane = tid & 63;
  const int rsel = lane & 15;
  const int ksel = (lane >> 4) << 3;
  const u16* qkb = (const u16*)qkt + h * 128;
  const long r0 = ((long)((tok_s[rsel] << 5) | rsel)) << 10;
  const long r1 = ((long)((tok_s[16 + rsel] << 5) | (16 + rsel))) << 10;

  f32x4 acc[2][2] = {{{0.f,0.f,0.f,0.f},{0.f,0.f,0.f,0.f}},
                     {{0.f,0.f,0.f,0.f},{0.f,0.f,0.f,0.f}}};
#pragma unroll
  for (int kc = 0; kc < 4; kc++) {
    int ko = kc * 32 + ksel;
    short8 a0 = *(const short8*)(qkb + r0 + ko);
    short8 a1 = *(const short8*)(qkb + r1 + ko);
    short8 b0 = *(const short8*)(qkb + r0 + 512 + ko);
    short8 b1 = *(const short8*)(qkb + r1 + 512 + ko);
    acc[0][0] = __builtin_amdgcn_mfma_f32_16x16x32_bf16(a0, b0, acc[0][0], 0, 0, 0);
    acc[0][1] = __builtin_amdgcn_mfma_f32_16x16x32_bf16(a0, b1, acc[0][1], 0, 0, 0);
    acc[1][0] = __builtin_amdgcn_mfma_f32_16x16x32_bf16(a1, b0, acc[1][0], 0, 0, 0);
    acc[1][1] = __builtin_amdgcn_mfma_f32_16x16x32_bf16(a1, b1, acc[1][1], 0, 0, 0);
  }

  const float scale = 0.088388347648318447f;  // 128^-0.5
  int j0 = lane & 15, j1 = 16 + j0;
  bool v0 = j0 < cnt, v1 = j1 < cnt;
  int rowq = (lane >> 4) << 2;
  float cs0 = 0.f, cs1 = 0.f;   // column-sum partials for cols j0, j1
#pragma unroll
  for (int ti = 0; ti < 2; ti++) {
    float s0[4], s1[4], mx[4], sm[4], e0[4], e1[4];
#pragma unroll
    for (int r = 0; r < 4; r++) {
      s0[r] = acc[ti][0][r] * scale;
      s1[r] = acc[ti][1][r] * scale;
      float a = v0 ? s0[r] : -1e30f;
      float b = v1 ? s1[r] : -1e30f;
      mx[r] = fmaxf(a, b);
    }
#pragma unroll
    for (int d = 1; d < 16; d <<= 1)
#pragma unroll
      for (int r = 0; r < 4; r++) mx[r] = fmaxf(mx[r], __shfl_xor(mx[r], d));
#pragma unroll
    for (int r = 0; r < 4; r++) {
      e0[r] = v0 ? __expf(s0[r] - mx[r]) : 0.f;
      e1[r] = v1 ? __expf(s1[r] - mx[r]) : 0.f;
      sm[r] = e0[r] + e1[r];
    }
#pragma unroll
    for (int d = 1; d < 16; d <<= 1)
#pragma unroll
      for (int r = 0; r < 4; r++) sm[r] += __shfl_xor(sm[r], d);
#pragma unroll
    for (int r = 0; r < 4; r++) {
      int row = ti * 16 + rowq + r;
      if (row < cnt) {
        float inv = 1.f / sm[r];
        cs0 += e0[r] * inv;
        cs1 += e1[r] * inv;
      }
    }
  }
  cs0 += __shfl_xor(cs0, 16); cs0 += __shfl_xor(cs0, 32);
  cs1 += __shfl_xor(cs1, 16); cs1 += __shfl_xor(cs1, 32);
  if (lane < 16) {
    float invc = 1.f / (float)cnt;
    wsum[h][lane] = cs0 * invc;
    wsum[h][16 + lane] = cs1 * invc;
  }
  __syncthreads();

  // z_h[e] = sum_j wsum[h][j] * emb[j][e]
  for (int e = tid; e < 512; e += 256) {
    float za0 = 0.f, za1 = 0.f, za2 = 0.f, za3 = 0.f;
    for (int j = 0; j < cnt; j++) {
      float ev = byte_emb[((long)tok_s[j] << 9) + e] + local_pos[((long)j << 9) + e];
      za0 += wsum[0][j] * ev;
      za1 += wsum[1][j] * ev;
      za2 += wsum[2][j] * ev;
      za3 += wsum[3][j] * ev;
    }
    long zb = (long)p * 2048;
    Z[zb + e]        = __float2bfloat16(za0);
    Z[zb + 512 + e]  = __float2bfloat16(za1);
    Z[zb + 1024 + e] = __float2bfloat16(za2);
    Z[zb + 1536 + e] = __float2bfloat16(za3);
  }
}

// ---------------------------------------------------------------------------
// Row LayerNorm: fp32 in, fp32 w/b; bf16 out (outb) or fp32 out (outf).
// ---------------------------------------------------------------------------
__global__ __launch_bounds__(256) void ln_kernel(
    const float* __restrict__ x, const float* __restrict__ w, const float* __restrict__ b,
    bf16* outb, float* outf, int N)
{
  __shared__ float red[8];
  __shared__ float mv[2];
  int row = blockIdx.x;
  const float* xr = x + (long)row * N;
  int tid = threadIdx.x, lane = tid & 63, wave = tid >> 6;
  float s = 0.f, s2 = 0.f;
  for (int c = tid; c < N; c += 256) { float v = xr[c]; s += v; s2 += v * v; }
  for (int o = 32; o; o >>= 1) { s += __shfl_down(s, o); s2 += __shfl_down(s2, o); }
  if (lane == 0) { red[wave] = s; red[4 + wave] = s2; }
  __syncthreads();
  if (tid == 0) {
    float ts = red[0] + red[1] + red[2] + red[3];
    float ts2 = red[4] + red[5] + red[6] + red[7];
    float mu = ts / N;
    float var = ts2 / N - mu * mu;
    mv[0] = mu; mv[1] = rsqrtf(var + 1e-5f);
  }
  __syncthreads();
  float mu = mv[0], rstd = mv[1];
  for (int c = tid; c < N; c += 256) {
    float v = (xr[c] - mu) * rstd * w[c] + b[c];
    if (outb) outb[(long)row * N + c] = __float2bfloat16(v);
    if (outf) outf[(long)row * N + c] = v;
  }
}

// ---------------------------------------------------------------------------
// Softmax over 1024 cols, in place on bf16 logits (scale folded in).
// ---------------------------------------------------------------------------
__global__ __launch_bounds__(256) void softmax_bf(u16* __restrict__ S)
{
  __shared__ float red[4], red2[4];
  long row = blockIdx.x;
  u16* sr = S + row * 1024;
  int tid = threadIdx.x, lane = tid & 63, wave = tid >> 6;
  const float scale = 0.10206207261596577f;  // 96^-0.5
  ushort4 raw = *(const ushort4*)(sr + tid * 4);
  float v[4] = {bf2f(raw.x) * scale, bf2f(raw.y) * scale, bf2f(raw.z) * scale, bf2f(raw.w) * scale};
  float m = fmaxf(fmaxf(v[0], v[1]), fmaxf(v[2], v[3]));
  for (int o = 32; o; o >>= 1) m = fmaxf(m, __shfl_down(m, o));
  if (lane == 0) red[wave] = m;
  __syncthreads();
  m = fmaxf(fmaxf(red[0], red[1]), fmaxf(red[2], red[3]));
  float s = 0.f;
#pragma unroll
  for (int k = 0; k < 4; k++) { v[k] = __expf(v[k] - m); s += v[k]; }
  for (int o = 32; o; o >>= 1) s += __shfl_down(s, o);
  if (lane == 0) red2[wave] = s;
  __syncthreads();
  s = red2[0] + red2[1] + red2[2] + red2[3];
  float inv = 1.f / s;
  ushort4 o4;
  o4.x = f2b(v[0] * inv); o4.y = f2b(v[1] * inv); o4.z = f2b(v[2] * inv); o4.w = f2b(v[3] * inv);
  *(ushort4*)(sr + tid * 4) = o4;
}

// ---------------------------------------------------------------------------
// Vt[d][k] = qkv[k][1536 + d]  (V part), 32x32 LDS tiles. bf16.
// ---------------------------------------------------------------------------
__global__ __launch_bounds__(256) void transpose_v(
    const bf16* __restrict__ qkv, bf16* __restrict__ Vt)
{
  __shared__ u16 tile[32][33];
  int k0 = blockIdx.x << 5;
  int d0 = blockIdx.y << 5;
  int tx = threadIdx.x & 31, ty = threadIdx.x >> 5;
  const u16* q = (const u16*)qkv;
  for (int i = ty; i < 32; i += 8)
    tile[i][tx] = q[(long)(k0 + i) * 2304 + 1536 + d0 + tx];
  __syncthreads();
  u16* vt = (u16*)Vt;
  for (int i = ty; i < 32; i += 8)
    vt[(long)(d0 + i) * 1024 + k0 + tx] = tile[tx][i];
}

extern "C" void kernel_launch(void* const* d_in, const int* in_sizes, int n_in,
                              void* d_out, int out_size, void* d_ws, size_t ws_size,
                              hipStream_t stream)
{
  const int*   tokens    = (const int*)d_in[0];
  const int*   lengths   = (const int*)d_in[1];
  const float* byte_emb  = (const float*)d_in[2];
  const float* local_pos = (const float*)d_in[3];
  const float* patch_pos = (const float*)d_in[4];
  const float* pa_qkv_w  = (const float*)d_in[5];
  const float* pa_qkv_b  = (const float*)d_in[6];
  const float* pa_out_w  = (const float*)d_in[7];
  const float* pa_out_b  = (const float*)d_in[8];
  const float* proj_w    = (const float*)d_in[9];
  const float* proj_b    = (const float*)d_in[10];
  const float* Wqkv      = (const float*)d_in[11];
  const float* Bqkv      = (const float*)d_in[12];
  const float* Wout      = (const float*)d_in[13];
  const float* Bout      = (const float*)d_in[14];
  const float* ln1w      = (const float*)d_in[15];
  const float* ln1b      = (const float*)d_in[16];
  const float* ln2w      = (const float*)d_in[17];
  const float* ln2b      = (const float*)d_in[18];
  const float* W1        = (const float*)d_in[19];
  const float* B1        = (const float*)d_in[20];
  const float* W2        = (const float*)d_in[21];
  const float* B2        = (const float*)d_in[22];
  const float* lnfw      = (const float*)d_in[23];
  const float* lnfb      = (const float*)d_in[24];

  char* ws = (char*)d_ws;
  const size_t MB = 1ull << 20;
  // ---- layout (<= 70 MB; r2-proven budget is >= 82 MB) ----
  bf16* qkT    = (bf16*)(ws);              // [0,16)  phase1 QK table [8192,1024]
  u16*  scores = (u16*)(ws);               // [0,16)  phase2 bf16 [8,1024,1024]
  bf16* qkvt   = (bf16*)(ws + 16 * MB);    // [16,21) [1024,2304]
  bf16* Vt     = (bf16*)(ws + 21 * MB);    // [21,23) [768,1024]
  bf16* attn   = (bf16*)(ws + 23 * MB);    // [23,25) [1024,768]
  bf16* ffb    = (bf16*)(ws + 25 * MB);    // [25,31) [1024,3072]
  float* h     = (float*)(ws + 31 * MB);   // [31,34) [1024,768] fp32
  bf16* hn     = (bf16*)(ws + 34 * MB);    // [34,36)
  bf16* embT   = (bf16*)(ws + 50 * MB);    // [50,58) phase1 emb table [8192,512]
  bf16* Z      = (bf16*)(ws + 64 * MB);    // [64,68) [1024,4,512]
  bf16* o_mean = (bf16*)(ws + 68 * MB);    // [68,69)
  bf16* t1     = (bf16*)(ws + 69 * MB);    // [69,70)

  // ---- phase 1 ----
  // embT[(t<<5)|l] = byte_emb[t] + local_pos[l]  (bf16, all 8192 combos)
  embed_table<<<2048, 256, 0, stream>>>(byte_emb, local_pos, embT);
  // qkT = embT @ Wqk^T + bqk   [8192,1024]; Wqk fp32, converted in staging
  gemm64<true><<<dim3(128, 16, 1), 256, 0, stream>>>(
      embT, 0, EE, pa_qkv_w, 0, EE, nullptr, qkT, 0, 1024,
      pa_qkv_b, 0, nullptr, 8192, 1024, EE, 0);
  patch_attn<<<PP, 256, 0, stream>>>(
      qkT, tokens, lengths, byte_emb, local_pos, Z);
  // o_mean[:, h*128:(h+1)*128] = Z[:,h,:] @ Wv_h^T + bv_h
  gemm64<true><<<dim3(16, 2, 4), 256, 0, stream>>>(
      Z, 512, 2048, pa_qkv_w + 1024L * EE, 128L * EE, EE,
      nullptr, o_mean, 128, EE, pa_qkv_b + 1024, 128, nullptr, PP, 128, EE, 0);
  // t1 = o_mean @ pa_out_w^T + b
  gemm64<true><<<dim3(16, 8, 1), 256, 0, stream>>>(
      o_mean, 0, EE, pa_out_w, 0, EE, nullptr, t1, 0, EE,
      pa_out_b, 0, nullptr, PP, EE, EE, 0);
  // h = t1 @ proj_w^T + b + patch_pos (fp32)
  gemm64<true><<<dim3(16, 12, 1), 256, 0, stream>>>(
      t1, 0, EE, proj_w, 0, EE, h, nullptr, 0, DD,
      proj_b, 0, patch_pos, PP, DD, EE, 0);

  // ---- phase 2: transformer encoder ----
  for (int i = 0; i < NLAYER; i++) {
    ln_kernel<<<PP, 256, 0, stream>>>(h, ln1w + i * DD, ln1b + i * DD, hn, nullptr, DD);
    // qkvt = hn @ Wqkv^T + b  (Wqkv fp32, converted in staging)
    gemm64<true><<<dim3(16, 36, 1), 256, 0, stream>>>(
        hn, 0, DD, Wqkv + (long)i * 2304 * DD, 0, DD, nullptr, qkvt, 0, 2304,
        Bqkv + i * 2304, 0, nullptr, PP, 2304, DD, 0);
    // scores[h] = Q_h @ K_h^T (bf16 logits)
    gemm64<false><<<dim3(16, 16, 8), 256, 0, stream>>>(
        qkvt, 96, 2304, qkvt + DD, 96, 2304, nullptr, (bf16*)scores, 1024L * 1024, 1024,
        nullptr, 0, nullptr, 1024, 1024, 96, 0);
    softmax_bf<<<8192, 256, 0, stream>>>(scores);
    transpose_v<<<dim3(32, 24), 256, 0, stream>>>(qkvt, Vt);
    // attn[:, h*96:(h+1)*96] = P_h @ V_h
    gemm64<false><<<dim3(16, 2, 8), 256, 0, stream>>>(
        (bf16*)scores, 1024L * 1024, 1024, Vt, 96L * 1024, 1024, nullptr, attn, 96, DD,
        nullptr, 0, nullptr, 1024, 96, 1024, 0);
    // h += attn @ Wout^T + bo   (split-K 2x, atomic accumulate into h)
    gemm64<true><<<dim3(16, 12, 2), 256, 0, stream>>>(
        attn, 384, DD, Wout + (long)i * DD * DD, 384, DD, h, nullptr, 0, DD,
        Bout + i * DD, 0, nullptr, PP, DD, 384, 2);
    ln_kernel<<<PP, 256, 0, stream>>>(h, ln2w + i * DD, ln2b + i * DD, hn, nullptr, DD);
    // ffb = gelu(hn @ W1^T + b1)
    gemm64<true><<<dim3(16, 48, 1), 256, 0, stream>>>(
        hn, 0, DD, W1 + (long)i * FFDIM * DD, 0, DD, nullptr, ffb, 0, FFDIM,
        B1 + i * FFDIM, 0, nullptr, PP, FFDIM, DD, 1);
    // h += ffb @ W2^T + b2   (split-K 4x, atomic accumulate into h)
    gemm64<true><<<dim3(16, 12, 4), 256, 0, stream>>>(
        ffb, 768, FFDIM, W2 + (long)i * DD * FFDIM, 768, FFDIM, h, nullptr, 0, DD,
        B2 + i * DD, 0, nullptr, PP, DD, 768, 2);
  }
  ln_kernel<<<PP, 256, 0, stream>>>(h, lnfw, lnfb, nullptr, (float*)d_out, DD);
}

// Round 3
// 988.620 us; speedup vs baseline: 1.2418x; 1.2418x over previous
//
#include <hip/hip_runtime.h>
#include <hip/hip_bf16.h>
#include <math.h>

typedef __hip_bfloat16 bf16;
typedef unsigned short u16;
typedef __attribute__((ext_vector_type(8))) short short8;
typedef __attribute__((ext_vector_type(4))) float f32x4;

#define PP 1024
#define LL 32
#define EE 512
#define DD 768
#define NLAYER 6
#define FFDIM 3072

__device__ __forceinline__ float bf2f(u16 u) { return __uint_as_float(((unsigned)u) << 16); }
// fp32 -> bf16 (RNE), finite inputs only
__device__ __forceinline__ u16 f2b(float x) {
  unsigned u = __float_as_uint(x);
  return (u16)((u + 0x7FFFu + ((u >> 16) & 1u)) >> 16);
}

// ---------------------------------------------------------------------------
// 4-region fp32 -> bf16 bulk convert. Region picked by blockIdx.y; counts in
// float4 units. Unused regions: n=0. One pass per layer: weight bf16 copies
// are then read (L2/L3-resident) by all 16 m-tiles of each GEMM -- cheaper
// than fusing the convert into B-staging (r2 post-mortem: fused = 16x
// redundant VALU + 2x fetch bytes, +~100us).
// ---------------------------------------------------------------------------
__global__ __launch_bounds__(256) void cvt4(
    const float* s0, const float* s1, const float* s2, const float* s3,
    u16* d0, u16* d1, u16* d2, u16* d3,
    int n0, int n1, int n2, int n3)
{
  int r = blockIdx.y;
  const float* s = r == 0 ? s0 : r == 1 ? s1 : r == 2 ? s2 : s3;
  u16* d        = r == 0 ? d0 : r == 1 ? d1 : r == 2 ? d2 : d3;
  int n4        = r == 0 ? n0 : r == 1 ? n1 : r == 2 ? n2 : n3;
  int i = blockIdx.x * 256 + threadIdx.x;
  if (i < n4) {
    float4 v = ((const float4*)s)[i];
    ushort4 o;
    o.x = f2b(v.x); o.y = f2b(v.y); o.z = f2b(v.z); o.w = f2b(v.w);
    ((ushort4*)d)[i] = o;
  }
}

// ---------------------------------------------------------------------------
// emb_table[r][k] = byte_emb[r>>5][k] + local_pos[r&31][k], bf16 out.
// [8192, 512]: one row per (token value, local position) pair.
// ---------------------------------------------------------------------------
__global__ __launch_bounds__(256) void embed_table(
    const float* __restrict__ be, const float* __restrict__ lp, bf16* __restrict__ T)
{
  int i = blockIdx.x * 256 + threadIdx.x;   // 8192 * 64 threads, 8 elems each
  int r = i >> 6, c = (i & 63) << 3;
  int t = r >> 5, l = r & 31;
  const float* bp = be + ((long)t << 9) + c;
  const float* pp = lp + ((long)l << 9) + c;
  float4 x0 = *(const float4*)bp, x1 = *(const float4*)(bp + 4);
  float4 y0 = *(const float4*)pp, y1 = *(const float4*)(pp + 4);
  short8 o;
  o[0] = (short)f2b(x0.x + y0.x); o[1] = (short)f2b(x0.y + y0.y);
  o[2] = (short)f2b(x0.z + y0.z); o[3] = (short)f2b(x0.w + y0.w);
  o[4] = (short)f2b(x1.x + y1.x); o[5] = (short)f2b(x1.y + y1.y);
  o[6] = (short)f2b(x1.z + y1.z); o[7] = (short)f2b(x1.w + y1.w);
  *(short8*)((u16*)T + ((long)r << 9) + c) = o;
}

// ---------------------------------------------------------------------------
// C = A @ B^T (+bias)(+addf)(gelu). A bf16 [M,K], B bf16 [N,K], fp32 accum.
// 64x64 tile / 256 threads, BK=64, double-buffered LDS, one barrier per
// chunk, next chunk's global loads issued before this chunk's MFMAs.
// blockIdx.x = m-tile (fastest): weight n-tiles stay L2-resident.
// act: 0 = none, 1 = gelu, 2 = split-K partial write (bias applied only for
// bz==0; Cf = partial pool, partial z at element offset bz*sCb; no atomics --
// the following ln_kernel sums the partials).
// Split-K / batching via blockIdx.z: sAb/sBb are element offsets (K-offset
// for split-K, batch stride otherwise); sCb is the C z/batch offset.
// M % 64 == 0; N, K guarded (K tail of 32).
// ---------------------------------------------------------------------------
__global__ __launch_bounds__(256) void gemm64(
    const bf16* A, long sAb, int lda,
    const bf16* B, long sBb, int ldb,
    float* Cf, bf16* Cb, long sCb, int ldc,
    const float* bias, int biasStride,
    const float* addf,
    int M, int N, int K, int act)
{
  __shared__ u16 As[2][64][72];   // stride 144 B: 16B-aligned, 2-way-only banks
  __shared__ u16 Bs[2][64][72];
  const int bz = blockIdx.z;
  const u16* Ap = (const u16*)A + (long)bz * sAb;
  const u16* Bp = (const u16*)B + (long)bz * sBb;
  const long coff = (long)bz * sCb;
  const int m0 = blockIdx.x << 6, n0 = blockIdx.y << 6;
  const int tid = threadIdx.x;
  const int wave = tid >> 6, lane = tid & 63;
  const int sr = tid >> 3;          // staging row 0..31 (and +32)
  const int scc = (tid & 7) << 3;   // staging col 0..56
  const int br0 = n0 + sr, br1 = n0 + sr + 32;
  const short8 zz = {0,0,0,0,0,0,0,0};
  f32x4 acc[4] = {{0.f,0.f,0.f,0.f},{0.f,0.f,0.f,0.f},{0.f,0.f,0.f,0.f},{0.f,0.f,0.f,0.f}};

  // prologue: stage chunk 0 into buffer 0
  {
    int ch = K < 64 ? K : 64;
    bool kv = scc < ch;
    short8 a0 = zz, a1 = zz, b0 = zz, b1 = zz;
    if (kv) {
      a0 = *(const short8*)(Ap + (long)(m0 + sr) * lda + scc);
      a1 = *(const short8*)(Ap + (long)(m0 + sr + 32) * lda + scc);
      if (br0 < N) b0 = *(const short8*)(Bp + (long)br0 * ldb + scc);
      if (br1 < N) b1 = *(const short8*)(Bp + (long)br1 * ldb + scc);
    }
    *(short8*)&As[0][sr][scc] = a0;
    *(short8*)&As[0][sr + 32][scc] = a1;
    *(short8*)&Bs[0][sr][scc] = b0;
    *(short8*)&Bs[0][sr + 32][scc] = b1;
  }
  __syncthreads();

  const int arow = (wave << 4) + (lane & 15);
  const int kq = (lane >> 4) << 3;
  int buf = 0;
  for (int k0 = 0; k0 < K; k0 += 64) {
    int knext = k0 + 64;
    bool more = knext < K;
    short8 a0 = zz, a1 = zz, b0 = zz, b1 = zz;
    if (more) {   // issue next chunk's loads before MFMAs (overlap)
      int ch = K - knext; if (ch > 64) ch = 64;
      bool kv = scc < ch;
      if (kv) {
        a0 = *(const short8*)(Ap + (long)(m0 + sr) * lda + knext + scc);
        a1 = *(const short8*)(Ap + (long)(m0 + sr + 32) * lda + knext + scc);
        if (br0 < N) b0 = *(const short8*)(Bp + (long)br0 * ldb + knext + scc);
        if (br1 < N) b1 = *(const short8*)(Bp + (long)br1 * ldb + knext + scc);
      }
    }
    int rem = K - k0; if (rem > 64) rem = 64;
    {
      short8 af = *(const short8*)&As[buf][arow][kq];
#pragma unroll
      for (int nt = 0; nt < 4; nt++) {
        short8 bfr = *(const short8*)&Bs[buf][(nt << 4) + (lane & 15)][kq];
        acc[nt] = __builtin_amdgcn_mfma_f32_16x16x32_bf16(af, bfr, acc[nt], 0, 0, 0);
      }
    }
    if (rem > 32) {
      short8 af = *(const short8*)&As[buf][arow][32 + kq];
#pragma unroll
      for (int nt = 0; nt < 4; nt++) {
        short8 bfr = *(const short8*)&Bs[buf][(nt << 4) + (lane & 15)][32 + kq];
        acc[nt] = __builtin_amdgcn_mfma_f32_16x16x32_bf16(af, bfr, acc[nt], 0, 0, 0);
      }
    }
    if (more) {
      int nb = buf ^ 1;
      *(short8*)&As[nb][sr][scc] = a0;
      *(short8*)&As[nb][sr + 32][scc] = a1;
      *(short8*)&Bs[nb][sr][scc] = b0;
      *(short8*)&Bs[nb][sr + 32][scc] = b1;
      __syncthreads();
      buf = nb;
    }
  }

  int rbase = m0 + (wave << 4) + ((lane >> 4) << 2);
#pragma unroll
  for (int nt = 0; nt < 4; nt++) {
    int c = n0 + (nt << 4) + (lane & 15);
    if (c >= N) continue;
    float bvl = bias ? bias[bz * biasStride + c] : 0.f;
    if (act == 2 && bz != 0) bvl = 0.f;
#pragma unroll
    for (int j = 0; j < 4; j++) {
      int r = rbase + j;
      long idx = coff + (long)r * ldc + c;
      float v = acc[nt][j] + bvl;
      if (addf) v += addf[idx];
      if (act == 1) v = 0.5f * v * (1.f + erff(v * 0.70710678118654752f));
      if (Cf) Cf[idx] = v;
      if (Cb) Cb[idx] = __float2bfloat16(v);
    }
  }
}

// ---------------------------------------------------------------------------
// Per-patch MHA over 32 bytes (4 heads, d=128) fused with masked mean.
// Q/K come from the per-(token,pos) table qkt [8192,1024]: row for byte j of
// patch p is (tokens[p*32+j]<<5)|j. MFMA QK^T (no LDS, no spills): wave =
// head; 2x2 16x16 C-tiles, 4 k-chunks.
// Softmax + column-mean via shuffle reductions in MFMA C-layout
// (row = (lane>>4)*4 + reg + ti*16, col = (lane&15) + tj*16).
// V path commuted: z_h = wsum_h @ emb (emb recomputed from fp32 tables).
// ---------------------------------------------------------------------------
__global__ __launch_bounds__(256) void patch_attn(
    const bf16* __restrict__ qkt,  // [8192, 1024] = [Q|K] per (token,pos)
    const int* __restrict__ tokens, const int* __restrict__ lengths,
    const float* __restrict__ byte_emb, const float* __restrict__ local_pos,
    bf16* __restrict__ Z)          // [1024, 4, 512]
{
  __shared__ float wsum[4][32];
  __shared__ int tok_s[32];
  __shared__ int cnt_s;
  int p = blockIdx.x;
  int tid = threadIdx.x;
  if (tid < 32) tok_s[tid] = tokens[p * 32 + tid];
  if (tid == 0) cnt_s = lengths[p];
  __syncthreads();
  int cnt = cnt_s;
  int h = tid >> 6, lane = tid & 63;
  const int rsel = lane & 15;
  const int ksel = (lane >> 4) << 3;
  const u16* qkb = (const u16*)qkt + h * 128;
  const long r0 = ((long)((tok_s[rsel] << 5) | rsel)) << 10;
  const long r1 = ((long)((tok_s[16 + rsel] << 5) | (16 + rsel))) << 10;

  f32x4 acc[2][2] = {{{0.f,0.f,0.f,0.f},{0.f,0.f,0.f,0.f}},
                     {{0.f,0.f,0.f,0.f},{0.f,0.f,0.f,0.f}}};
#pragma unroll
  for (int kc = 0; kc < 4; kc++) {
    int ko = kc * 32 + ksel;
    short8 a0 = *(const short8*)(qkb + r0 + ko);
    short8 a1 = *(const short8*)(qkb + r1 + ko);
    short8 b0 = *(const short8*)(qkb + r0 + 512 + ko);
    short8 b1 = *(const short8*)(qkb + r1 + 512 + ko);
    acc[0][0] = __builtin_amdgcn_mfma_f32_16x16x32_bf16(a0, b0, acc[0][0], 0, 0, 0);
    acc[0][1] = __builtin_amdgcn_mfma_f32_16x16x32_bf16(a0, b1, acc[0][1], 0, 0, 0);
    acc[1][0] = __builtin_amdgcn_mfma_f32_16x16x32_bf16(a1, b0, acc[1][0], 0, 0, 0);
    acc[1][1] = __builtin_amdgcn_mfma_f32_16x16x32_bf16(a1, b1, acc[1][1], 0, 0, 0);
  }

  const float scale = 0.088388347648318447f;  // 128^-0.5
  int j0 = lane & 15, j1 = 16 + j0;
  bool v0 = j0 < cnt, v1 = j1 < cnt;
  int rowq = (lane >> 4) << 2;
  float cs0 = 0.f, cs1 = 0.f;   // column-sum partials for cols j0, j1
#pragma unroll
  for (int ti = 0; ti < 2; ti++) {
    float s0[4], s1[4], mx[4], sm[4], e0[4], e1[4];
#pragma unroll
    for (int r = 0; r < 4; r++) {
      s0[r] = acc[ti][0][r] * scale;
      s1[r] = acc[ti][1][r] * scale;
      float a = v0 ? s0[r] : -1e30f;
      float b = v1 ? s1[r] : -1e30f;
      mx[r] = fmaxf(a, b);
    }
#pragma unroll
    for (int d = 1; d < 16; d <<= 1)
#pragma unroll
      for (int r = 0; r < 4; r++) mx[r] = fmaxf(mx[r], __shfl_xor(mx[r], d));
#pragma unroll
    for (int r = 0; r < 4; r++) {
      e0[r] = v0 ? __expf(s0[r] - mx[r]) : 0.f;
      e1[r] = v1 ? __expf(s1[r] - mx[r]) : 0.f;
      sm[r] = e0[r] + e1[r];
    }
#pragma unroll
    for (int d = 1; d < 16; d <<= 1)
#pragma unroll
      for (int r = 0; r < 4; r++) sm[r] += __shfl_xor(sm[r], d);
#pragma unroll
    for (int r = 0; r < 4; r++) {
      int row = ti * 16 + rowq + r;
      if (row < cnt) {
        float inv = 1.f / sm[r];
        cs0 += e0[r] * inv;
        cs1 += e1[r] * inv;
      }
    }
  }
  cs0 += __shfl_xor(cs0, 16); cs0 += __shfl_xor(cs0, 32);
  cs1 += __shfl_xor(cs1, 16); cs1 += __shfl_xor(cs1, 32);
  if (lane < 16) {
    float invc = 1.f / (float)cnt;
    wsum[h][lane] = cs0 * invc;
    wsum[h][16 + lane] = cs1 * invc;
  }
  __syncthreads();

  // z_h[e] = sum_j wsum[h][j] * emb[j][e]
  for (int e = tid; e < 512; e += 256) {
    float za0 = 0.f, za1 = 0.f, za2 = 0.f, za3 = 0.f;
    for (int j = 0; j < cnt; j++) {
      float ev = byte_emb[((long)tok_s[j] << 9) + e] + local_pos[((long)j << 9) + e];
      za0 += wsum[0][j] * ev;
      za1 += wsum[1][j] * ev;
      za2 += wsum[2][j] * ev;
      za3 += wsum[3][j] * ev;
    }
    long zb = (long)p * 2048;
    Z[zb + e]        = __float2bfloat16(za0);
    Z[zb + 512 + e]  = __float2bfloat16(za1);
    Z[zb + 1024 + e] = __float2bfloat16(za2);
    Z[zb + 1536 + e] = __float2bfloat16(za3);
  }
}

// ---------------------------------------------------------------------------
// Row LayerNorm over 768 cols, with optional fused residual-partial sum:
// v = x[row] + a0 + a1 + a2 + a3 (each nullable); if hout, hout[row] = v
// (persist updated residual); then LN(v)*w+b -> outb (bf16) / outf (fp32).
// 256 threads, 3 cols/thread, register-resident (static unroll -- no scratch).
// ---------------------------------------------------------------------------
__global__ __launch_bounds__(256) void ln_kernel(
    const float* __restrict__ x,
    const float* __restrict__ a0, const float* __restrict__ a1,
    const float* __restrict__ a2, const float* __restrict__ a3,
    float* __restrict__ hout,
    const float* __restrict__ w, const float* __restrict__ b,
    bf16* outb, float* outf)
{
  __shared__ float red[8];
  __shared__ float mv[2];
  int row = blockIdx.x;
  long base = (long)row * DD;
  int tid = threadIdx.x, lane = tid & 63, wave = tid >> 6;
  float vv[3];
  float s = 0.f, s2 = 0.f;
#pragma unroll
  for (int j = 0; j < 3; j++) {
    long c = base + tid + j * 256;
    float v = x[c];
    if (a0) v += a0[c];
    if (a1) v += a1[c];
    if (a2) v += a2[c];
    if (a3) v += a3[c];
    if (hout) hout[c] = v;
    vv[j] = v; s += v; s2 += v * v;
  }
  for (int o = 32; o; o >>= 1) { s += __shfl_down(s, o); s2 += __shfl_down(s2, o); }
  if (lane == 0) { red[wave] = s; red[4 + wave] = s2; }
  __syncthreads();
  if (tid == 0) {
    float ts = red[0] + red[1] + red[2] + red[3];
    float ts2 = red[4] + red[5] + red[6] + red[7];
    float mu = ts / DD;
    float var = ts2 / DD - mu * mu;
    mv[0] = mu; mv[1] = rsqrtf(var + 1e-5f);
  }
  __syncthreads();
  float mu = mv[0], rstd = mv[1];
#pragma unroll
  for (int j = 0; j < 3; j++) {
    int c = tid + j * 256;
    float v = (vv[j] - mu) * rstd * w[c] + b[c];
    if (outb) outb[base + c] = __float2bfloat16(v);
    if (outf) outf[base + c] = v;
  }
}

// ---------------------------------------------------------------------------
// Softmax over 1024 cols, in place on bf16 logits (scale folded in).
// ---------------------------------------------------------------------------
__global__ __launch_bounds__(256) void softmax_bf(u16* __restrict__ S)
{
  __shared__ float red[4], red2[4];
  long row = blockIdx.x;
  u16* sr = S + row * 1024;
  int tid = threadIdx.x, lane = tid & 63, wave = tid >> 6;
  const float scale = 0.10206207261596577f;  // 96^-0.5
  ushort4 raw = *(const ushort4*)(sr + tid * 4);
  float v[4] = {bf2f(raw.x) * scale, bf2f(raw.y) * scale, bf2f(raw.z) * scale, bf2f(raw.w) * scale};
  float m = fmaxf(fmaxf(v[0], v[1]), fmaxf(v[2], v[3]));
  for (int o = 32; o; o >>= 1) m = fmaxf(m, __shfl_down(m, o));
  if (lane == 0) red[wave] = m;
  __syncthreads();
  m = fmaxf(fmaxf(red[0], red[1]), fmaxf(red[2], red[3]));
  float s = 0.f;
#pragma unroll
  for (int k = 0; k < 4; k++) { v[k] = __expf(v[k] - m); s += v[k]; }
  for (int o = 32; o; o >>= 1) s += __shfl_down(s, o);
  if (lane == 0) red2[wave] = s;
  __syncthreads();
  s = red2[0] + red2[1] + red2[2] + red2[3];
  float inv = 1.f / s;
  ushort4 o4;
  o4.x = f2b(v[0] * inv); o4.y = f2b(v[1] * inv); o4.z = f2b(v[2] * inv); o4.w = f2b(v[3] * inv);
  *(ushort4*)(sr + tid * 4) = o4;
}

// ---------------------------------------------------------------------------
// Vt[d][k] = qkv[k][1536 + d]  (V part), 32x32 LDS tiles. bf16.
// ---------------------------------------------------------------------------
__global__ __launch_bounds__(256) void transpose_v(
    const bf16* __restrict__ qkv, bf16* __restrict__ Vt)
{
  __shared__ u16 tile[32][33];
  int k0 = blockIdx.x << 5;
  int d0 = blockIdx.y << 5;
  int tx = threadIdx.x & 31, ty = threadIdx.x >> 5;
  const u16* q = (const u16*)qkv;
  for (int i = ty; i < 32; i += 8)
    tile[i][tx] = q[(long)(k0 + i) * 2304 + 1536 + d0 + tx];
  __syncthreads();
  u16* vt = (u16*)Vt;
  for (int i = ty; i < 32; i += 8)
    vt[(long)(d0 + i) * 1024 + k0 + tx] = tile[tx][i];
}

extern "C" void kernel_launch(void* const* d_in, const int* in_sizes, int n_in,
                              void* d_out, int out_size, void* d_ws, size_t ws_size,
                              hipStream_t stream)
{
  const int*   tokens    = (const int*)d_in[0];
  const int*   lengths   = (const int*)d_in[1];
  const float* byte_emb  = (const float*)d_in[2];
  const float* local_pos = (const float*)d_in[3];
  const float* patch_pos = (const float*)d_in[4];
  const float* pa_qkv_w  = (const float*)d_in[5];
  const float* pa_qkv_b  = (const float*)d_in[6];
  const float* pa_out_w  = (const float*)d_in[7];
  const float* pa_out_b  = (const float*)d_in[8];
  const float* proj_w    = (const float*)d_in[9];
  const float* proj_b    = (const float*)d_in[10];
  const float* Wqkv      = (const float*)d_in[11];
  const float* Bqkv      = (const float*)d_in[12];
  const float* Wout      = (const float*)d_in[13];
  const float* Bout      = (const float*)d_in[14];
  const float* ln1w      = (const float*)d_in[15];
  const float* ln1b      = (const float*)d_in[16];
  const float* ln2w      = (const float*)d_in[17];
  const float* ln2b      = (const float*)d_in[18];
  const float* W1        = (const float*)d_in[19];
  const float* B1        = (const float*)d_in[20];
  const float* W2        = (const float*)d_in[21];
  const float* B2        = (const float*)d_in[22];
  const float* lnfw      = (const float*)d_in[23];
  const float* lnfb      = (const float*)d_in[24];

  char* ws = (char*)d_ws;
  const size_t MB = 1ull << 20;
  // ---- layout (<= 73 MB; proven budget >= 82 MB) ----
  bf16* qkT    = (bf16*)(ws);              // [0,16)  phase1 QK table [8192,1024]
  u16*  scores = (u16*)(ws);               // [0,16)  phase2 bf16 [8,1024,1024]
  bf16* qkvt   = (bf16*)(ws + 16 * MB);    // [16,21) [1024,2304]
  bf16* Vt     = (bf16*)(ws + 21 * MB);    // [21,23) [768,1024]
  bf16* attn   = (bf16*)(ws + 23 * MB);    // [23,25) [1024,768]
  bf16* ffb    = (bf16*)(ws + 25 * MB);    // [25,31) [1024,3072]
  float* h     = (float*)(ws + 31 * MB);   // [31,34) [1024,768] fp32
  bf16* hn     = (bf16*)(ws + 34 * MB);    // [34,36)
  u16*  Lw     = (u16*)(ws + 36 * MB);     // [36,50) per-layer bf16 weights
  bf16* embT   = (bf16*)(ws + 50 * MB);    // [50,58) phase1 emb table [8192,512]
  float* hp    = (float*)(ws + 58 * MB);   // [58,70) split-K partials 4x[1024,768] fp32 (phase2)
  bf16* Z      = (bf16*)(ws + 64 * MB);    // [64,68) [1024,4,512] (phase1 only; overlaps hp)
  bf16* o_mean = (bf16*)(ws + 68 * MB);    // [68,69) (phase1)
  bf16* t1     = (bf16*)(ws + 69 * MB);    // [69,70) (phase1)
  u16*  P1w    = (u16*)(ws + 70 * MB);     // [70,73) phase1 bf16 weights

  const long PSTRIDE = (long)PP * DD;      // partial slot stride (elements)

  // per-layer pool offsets (u16 elements)
  const long oLQKV = 0;          // [2304,768]
  const long oLOUT = 1769472;    // [768,768]
  const long oLW1  = 2359296;    // [3072,768]
  const long oLW2  = 4718592;    // [768,3072]
  // phase-1 pool offsets
  const long oPAQ  = 0;          // [1536,512]
  const long oPAO  = 786432;     // [512,512]
  const long oPRJ  = 1048576;    // [768,512]

  // ---- phase 1 ----
  cvt4<<<dim3(768, 3), 256, 0, stream>>>(
      pa_qkv_w, pa_out_w, proj_w, nullptr,
      P1w + oPAQ, P1w + oPAO, P1w + oPRJ, nullptr,
      786432 / 4, 262144 / 4, 393216 / 4, 0);
  // embT[(t<<5)|l] = byte_emb[t] + local_pos[l]  (bf16, all 8192 combos)
  embed_table<<<2048, 256, 0, stream>>>(byte_emb, local_pos, embT);
  // qkT = embT @ Wqk^T + bqk   [8192,1024]: 4x fewer FLOPs than per-byte Q/K
  gemm64<<<dim3(128, 16, 1), 256, 0, stream>>>(
      embT, 0, EE, (bf16*)(P1w + oPAQ), 0, EE, nullptr, qkT, 0, 1024,
      pa_qkv_b, 0, nullptr, 8192, 1024, EE, 0);
  patch_attn<<<PP, 256, 0, stream>>>(
      qkT, tokens, lengths, byte_emb, local_pos, Z);
  // o_mean[:, h*128:(h+1)*128] = Z[:,h,:] @ Wv_h^T + bv_h
  gemm64<<<dim3(16, 2, 4), 256, 0, stream>>>(
      Z, 512, 2048, (bf16*)(P1w + oPAQ + 1024L * EE), 128L * EE, EE,
      nullptr, o_mean, 128, EE, pa_qkv_b + 1024, 128, nullptr, PP, 128, EE, 0);
  // t1 = o_mean @ pa_out_w^T + b
  gemm64<<<dim3(16, 8, 1), 256, 0, stream>>>(
      o_mean, 0, EE, (bf16*)(P1w + oPAO), 0, EE, nullptr, t1, 0, EE,
      pa_out_b, 0, nullptr, PP, EE, EE, 0);
  // h = t1 @ proj_w^T + b + patch_pos (fp32)
  gemm64<<<dim3(16, 12, 1), 256, 0, stream>>>(
      t1, 0, EE, (bf16*)(P1w + oPRJ), 0, EE, h, nullptr, 0, DD,
      proj_b, 0, patch_pos, PP, DD, EE, 0);

  // ---- phase 2: transformer encoder ----
  for (int i = 0; i < NLAYER; i++) {
    cvt4<<<dim3(2304, 4), 256, 0, stream>>>(
        Wqkv + (long)i * 2304 * DD, Wout + (long)i * DD * DD,
        W1 + (long)i * FFDIM * DD, W2 + (long)i * DD * FFDIM,
        Lw + oLQKV, Lw + oLOUT, Lw + oLW1, Lw + oLW2,
        1769472 / 4, 589824 / 4, 2359296 / 4, 2359296 / 4);
    // ln1: for i>0 also folds in previous layer's ff2 partials and updates h
    if (i == 0)
      ln_kernel<<<PP, 256, 0, stream>>>(h, nullptr, nullptr, nullptr, nullptr,
                                        nullptr, ln1w + i * DD, ln1b + i * DD, hn, nullptr);
    else
      ln_kernel<<<PP, 256, 0, stream>>>(h, hp, hp + PSTRIDE, hp + 2 * PSTRIDE, hp + 3 * PSTRIDE,
                                        h, ln1w + i * DD, ln1b + i * DD, hn, nullptr);
    gemm64<<<dim3(16, 36, 1), 256, 0, stream>>>(
        hn, 0, DD, (bf16*)(Lw + oLQKV), 0, DD, nullptr, qkvt, 0, 2304,
        Bqkv + i * 2304, 0, nullptr, PP, 2304, DD, 0);
    // scores[h] = Q_h @ K_h^T (bf16 logits)
    gemm64<<<dim3(16, 16, 8), 256, 0, stream>>>(
        qkvt, 96, 2304, qkvt + DD, 96, 2304, nullptr, (bf16*)scores, 1024L * 1024, 1024,
        nullptr, 0, nullptr, 1024, 1024, 96, 0);
    softmax_bf<<<8192, 256, 0, stream>>>(scores);
    transpose_v<<<dim3(32, 24), 256, 0, stream>>>(qkvt, Vt);
    // attn[:, h*96:(h+1)*96] = P_h @ V_h
    gemm64<<<dim3(16, 2, 8), 256, 0, stream>>>(
        (bf16*)scores, 1024L * 1024, 1024, Vt, 96L * 1024, 1024, nullptr, attn, 96, DD,
        nullptr, 0, nullptr, 1024, 96, 1024, 0);
    // out-proj split-K 2x -> partials hp[0..1] (no atomics; summed in ln2)
    gemm64<<<dim3(16, 12, 2), 256, 0, stream>>>(
        attn, 384, DD, (bf16*)(Lw + oLOUT), 384, DD, hp, nullptr, PSTRIDE, DD,
        Bout + i * DD, 0, nullptr, PP, DD, 384, 2);
    // ln2: h += p0 + p1, then LN -> hn
    ln_kernel<<<PP, 256, 0, stream>>>(h, hp, hp + PSTRIDE, nullptr, nullptr,
                                      h, ln2w + i * DD, ln2b + i * DD, hn, nullptr);
    // ffb = gelu(hn @ W1^T + b1)
    gemm64<<<dim3(16, 48, 1), 256, 0, stream>>>(
        hn, 0, DD, (bf16*)(Lw + oLW1), 0, DD, nullptr, ffb, 0, FFDIM,
        B1 + i * FFDIM, 0, nullptr, PP, FFDIM, DD, 1);
    // ff2 split-K 4x -> partials hp[0..3] (summed in next ln1 / final ln)
    gemm64<<<dim3(16, 12, 4), 256, 0, stream>>>(
        ffb, 768, FFDIM, (bf16*)(Lw + oLW2), 768, FFDIM, hp, nullptr, PSTRIDE, DD,
        B2 + i * DD, 0, nullptr, PP, DD, 768, 2);
  }
  // final LN folds in layer-5 ff2 partials
  ln_kernel<<<PP, 256, 0, stream>>>(h, hp, hp + PSTRIDE, hp + 2 * PSTRIDE, hp + 3 * PSTRIDE,
                                    nullptr, lnfw, lnfb, nullptr, (float*)d_out);
}